// Round 2
// baseline (88.937 us; speedup 1.0000x reference)
//
#include <hip/hip_runtime.h>
#include <stdint.h>
#include <stddef.h>

// BlockLinear: out[b, g*512+n] = sum_m x[b, g*512+m] * blocks[g, m, n]
// G=8, M=N=512, TOKENS=8192. fp32 in/out; compute in bf16 MFMA.
// Round 2: double-buffered 1-barrier pipeline; B via global_load_lds
// (pre-swizzled global source), A reg-staged with cvt after compute.

typedef __attribute__((ext_vector_type(8))) short sv8;   // 8 x bf16 fragment
typedef __attribute__((ext_vector_type(4))) float fv4;   // 4 x f32 accum

__device__ __forceinline__ uint32_t f2bf(float f) {
    union { float f; uint32_t u; } v; v.f = f;
    uint32_t u = v.u;
    u += 0x7FFFu + ((u >> 16) & 1u);   // RNE
    return u >> 16;
}
__device__ __forceinline__ uint32_t pk2(float a, float b) {
    return f2bf(a) | (f2bf(b) << 16);
}

__device__ __forceinline__ void gl_lds16(const void* g, void* lds) {
    __builtin_amdgcn_global_load_lds(
        (const __attribute__((address_space(1))) void*)g,
        (__attribute__((address_space(3))) void*)lds, 16, 0, 0);
}

// blocksT[g][n][k] (bf16) = blocks[g][k][n] (f32)
__global__ void bl_transpose(const float* __restrict__ blocks,
                             unsigned short* __restrict__ bT) {
    __shared__ float tile[64][65];
    const int g  = blockIdx.z;
    const int k0 = blockIdx.y * 64;
    const int n0 = blockIdx.x * 64;
    const float* src = blocks + (size_t)g * 512 * 512;
    unsigned short* dst = bT + (size_t)g * 512 * 512;
    const int lane = threadIdx.x & 63;
    const int r0   = threadIdx.x >> 6;   // 0..3
    for (int r = r0; r < 64; r += 4)
        tile[r][lane] = src[(size_t)(k0 + r) * 512 + n0 + lane];
    __syncthreads();
    for (int r = r0; r < 64; r += 4)
        dst[(size_t)(n0 + r) * 512 + k0 + lane] = (unsigned short)f2bf(tile[lane][r]);
}

// Main GEMM: BM=128, BN=256, BK=64, 512 threads (8 waves, 2x4 wave grid,
// 64x64 per wave = 4x4 fragments of 16x16x32 bf16 MFMA).
// Double-buffered LDS (96 KiB -> 1 block/CU), one barrier per K-step.
__global__ __launch_bounds__(512, 2) void bl_gemm(
    const float* __restrict__ x,            // [8192][4096]
    const unsigned short* __restrict__ bT,  // [8][512 n][512 k] bf16
    float* __restrict__ out)                // [8192][4096]
{
    __shared__ __align__(16) unsigned short As[2][128 * 64];  // [row m][k], XOR-swizzled 16B slots
    __shared__ __align__(16) unsigned short Bs[2][256 * 64];  // [row n][k], XOR-swizzled 16B slots

    const int bid = blockIdx.x;
    const int g   = bid & 7;          // group == XCD (round-robin dispatch)
    const int rem = bid >> 3;
    const int nt  = rem & 1;
    const int mt  = rem >> 1;         // 0..63

    const int tid  = threadIdx.x;
    const int lane = tid & 63;
    const int wid  = tid >> 6;        // 0..7
    const int wm   = wid >> 2;        // 0..1
    const int wn   = wid & 3;         // 0..3

    fv4 acc[4][4];
#pragma unroll
    for (int i = 0; i < 4; ++i)
#pragma unroll
        for (int j = 0; j < 4; ++j)
            acc[i][j] = (fv4){0.f, 0.f, 0.f, 0.f};

    const float* xg = x + (size_t)(mt * 128) * 4096 + g * 512;
    const unsigned short* bg = bT + ((size_t)g * 512 + nt * 256) * 512;

    // ---- A staging addressing (reg-staged, cvt to bf16) ----
    const int arow = tid >> 3;        // 0..63 (rows arow and arow+64)
    const int ac8  = tid & 7;         // 16B chunk within 64-elem k-row
    const float* aSrc = xg + (size_t)arow * 4096 + ac8 * 8;
    const int aSlot = ac8 ^ (arow & 7);               // (arow+64)&7 == arow&7
    const int aOff0 = arow * 128 + aSlot * 16;        // byte offsets in As[c]
    const int aOff1 = (arow + 64) * 128 + aSlot * 16;

    // ---- B staging addressing (global_load_lds, pre-swizzled source) ----
    // LDS[row][slot] must hold global chunk (slot ^ (row&7)); dest is linear:
    // lane l -> row = wid*32 + p*8 + (l>>3), slot = l&7  (row&7 == (l>>3)&7)
    const int brow   = wid * 32 + (lane >> 3);
    const int bchunk = (lane & 7) ^ ((lane >> 3) & 7);
    const unsigned short* bSrc = bg + (size_t)brow * 512 + bchunk * 8;

    float4 ar[2][2];   // prefetched A regs (2 rows x 32B)

    auto issueA = [&](int kt) {
        const float* s0 = aSrc + kt * 64;
        const float* s1 = aSrc + (size_t)64 * 4096 + kt * 64;
        ar[0][0] = *(const float4*)s0;
        ar[0][1] = *(const float4*)(s0 + 4);
        ar[1][0] = *(const float4*)s1;
        ar[1][1] = *(const float4*)(s1 + 4);
    };
    auto issueB = [&](int kt, int c) {
#pragma unroll
        for (int p = 0; p < 4; ++p)
            gl_lds16(bSrc + (size_t)p * 8 * 512 + kt * 64,
                     (void*)((char*)&Bs[c][0] + (wid * 32 + p * 8) * 128));
    };
    auto writeA = [&](int c) {
        uint4 w0, w1;
        w0.x = pk2(ar[0][0].x, ar[0][0].y); w0.y = pk2(ar[0][0].z, ar[0][0].w);
        w0.z = pk2(ar[0][1].x, ar[0][1].y); w0.w = pk2(ar[0][1].z, ar[0][1].w);
        w1.x = pk2(ar[1][0].x, ar[1][0].y); w1.y = pk2(ar[1][0].z, ar[1][0].w);
        w1.z = pk2(ar[1][1].x, ar[1][1].y); w1.w = pk2(ar[1][1].z, ar[1][1].w);
        *(uint4*)((char*)&As[c][0] + aOff0) = w0;
        *(uint4*)((char*)&As[c][0] + aOff1) = w1;
    };
    auto compute = [&](int c) {
        const int lr = lane & 15;
        const int lg = lane >> 4;
#pragma unroll
        for (int kk = 0; kk < 2; ++kk) {
            const int ks = kk * 4 + lg;   // 16B k-slot (8 bf16)
            sv8 a[4], b[4];
#pragma unroll
            for (int mi = 0; mi < 4; ++mi) {
                const int row = wm * 64 + mi * 16 + lr;
                a[mi] = *(const sv8*)((const char*)&As[c][0] + row * 128 + ((ks ^ (row & 7)) * 16));
            }
#pragma unroll
            for (int ni = 0; ni < 4; ++ni) {
                const int row = wn * 64 + ni * 16 + lr;
                b[ni] = *(const sv8*)((const char*)&Bs[c][0] + row * 128 + ((ks ^ (row & 7)) * 16));
            }
#pragma unroll
            for (int mi = 0; mi < 4; ++mi)
#pragma unroll
                for (int ni = 0; ni < 4; ++ni)
                    acc[mi][ni] = __builtin_amdgcn_mfma_f32_16x16x32_bf16(
                        a[mi], b[ni], acc[mi][ni], 0, 0, 0);
        }
    };

    // ---- prologue: stage tile 0 into buffer 0 ----
    issueA(0);
    issueB(0, 0);
    writeA(0);
    __syncthreads();   // implicit vmcnt(0) drains B(0); lgkmcnt drains A writes

    int c = 0;
    for (int kt = 0; kt < 7; ++kt) {
        issueA(kt + 1);          // global loads for next tile in flight...
        issueB(kt + 1, c ^ 1);   // ...during compute of current tile
        compute(c);
        writeA(c ^ 1);           // A load latency hidden under compute
        __syncthreads();
        c ^= 1;
    }
    compute(c);   // last tile, no prefetch

    // ---- epilogue: D layout col=lane&15, row=(lane>>4)*4+q ----
    const int lr = lane & 15;
    const int lg = lane >> 4;
    float* og = out + (size_t)(mt * 128) * 4096 + g * 512 + nt * 256;
#pragma unroll
    for (int mi = 0; mi < 4; ++mi)
#pragma unroll
        for (int ni = 0; ni < 4; ++ni)
#pragma unroll
            for (int q = 0; q < 4; ++q) {
                const int row = wm * 64 + mi * 16 + lg * 4 + q;
                const int col = wn * 64 + ni * 16 + lr;
                og[(size_t)row * 4096 + col] = acc[mi][ni][q];
            }
}

// Safety net if ws is too small for the bf16 transposed blocks (4 MiB).
__global__ void bl_fallback(const float* __restrict__ x,
                            const float* __restrict__ blocks,
                            float* __restrict__ out) {
    const int o = blockIdx.x * 256 + threadIdx.x;
    const int col = o & 4095;
    const int row = o >> 12;
    const int g = col >> 9;
    const int n = col & 511;
    const float* xr = x + (size_t)row * 4096 + g * 512;
    const float* wp = blocks + (size_t)g * 512 * 512 + n;
    float s = 0.f;
    for (int m = 0; m < 512; ++m) s += xr[m] * wp[(size_t)m * 512];
    out[o] = s;
}

extern "C" void kernel_launch(void* const* d_in, const int* in_sizes, int n_in,
                              void* d_out, int out_size, void* d_ws, size_t ws_size,
                              hipStream_t stream) {
    const float* x      = (const float*)d_in[0];
    const float* blocks = (const float*)d_in[1];
    float* out          = (float*)d_out;

    const size_t need = (size_t)8 * 512 * 512 * sizeof(unsigned short); // 4 MiB
    if (ws_size >= need) {
        unsigned short* bT = (unsigned short*)d_ws;
        bl_transpose<<<dim3(8, 8, 8), 256, 0, stream>>>(blocks, bT);
        bl_gemm<<<1024, 512, 0, stream>>>(x, bT, out);
    } else {
        bl_fallback<<<(8192 * 4096) / 256, 256, 0, stream>>>(x, blocks, out);
    }
}

// Round 3
// 84.704 us; speedup vs baseline: 1.0500x; 1.0500x over previous
//
#include <hip/hip_runtime.h>
#include <stdint.h>
#include <stddef.h>

// BlockLinear: out[b, g*512+n] = sum_m x[b, g*512+m] * blocks[g, m, n]
// G=8, M=N=512, TOKENS=8192. fp32 in/out; compute in bf16 MFMA.
// Round 3: 8-phase 256x256 tile, counted-vmcnt pipeline (T2+T3+T4+T5+T14).

typedef __attribute__((ext_vector_type(8))) short sv8;   // 8 x bf16 fragment
typedef __attribute__((ext_vector_type(4))) float fv4;   // 4 x f32 accum

__device__ __forceinline__ uint32_t f2bf(float f) {
    union { float f; uint32_t u; } v; v.f = f;
    uint32_t u = v.u;
    u += 0x7FFFu + ((u >> 16) & 1u);   // RNE
    return u >> 16;
}
__device__ __forceinline__ uint32_t pk2(float a, float b) {
    return f2bf(a) | (f2bf(b) << 16);
}
__device__ __forceinline__ void gl_lds16(const void* g, void* lds) {
    __builtin_amdgcn_global_load_lds(
        (const __attribute__((address_space(1))) void*)g,
        (__attribute__((address_space(3))) void*)lds, 16, 0, 0);
}

// blocksT[g][n][k] (bf16) = blocks[g][k][n] (f32)
__global__ void bl_transpose(const float* __restrict__ blocks,
                             unsigned short* __restrict__ bT) {
    __shared__ float tile[64][65];
    const int g  = blockIdx.z;
    const int k0 = blockIdx.y * 64;
    const int n0 = blockIdx.x * 64;
    const float* src = blocks + (size_t)g * 512 * 512;
    unsigned short* dst = bT + (size_t)g * 512 * 512;
    const int lane = threadIdx.x & 63;
    const int r0   = threadIdx.x >> 6;   // 0..3
    for (int r = r0; r < 64; r += 4)
        tile[r][lane] = src[(size_t)(k0 + r) * 512 + n0 + lane];
    __syncthreads();
    for (int r = r0; r < 64; r += 4)
        dst[(size_t)(n0 + r) * 512 + k0 + lane] = (unsigned short)f2bf(tile[lane][r]);
}

#define BAR()   __builtin_amdgcn_s_barrier()
#define SB0()   __builtin_amdgcn_sched_barrier(0)
#define LGKM0() do { asm volatile("s_waitcnt lgkmcnt(0)" ::: "memory"); SB0(); } while (0)
#define VM(N)   asm volatile("s_waitcnt vmcnt(" #N ")" ::: "memory")
#define PRIO1() __builtin_amdgcn_s_setprio(1)
#define PRIO0() __builtin_amdgcn_s_setprio(0)

// Main GEMM: BM=256, BN=256, BK=64, 512 threads (8 waves, 2Mx4N grid,
// wave tile 128x64 = 8x4 fragments of 16x16x32 bf16 MFMA).
// Double-buffered LDS (128 KiB, 1 block/CU), 4 quadrant-phases per K-tile,
// counted vmcnt: A loads 2 tiles ahead, B gl_lds 1 tile ahead.
__global__ __launch_bounds__(512, 2) void bl_gemm(
    const float* __restrict__ x,            // [8192][4096]
    const unsigned short* __restrict__ bT,  // [8][512 n][512 k] bf16
    float* __restrict__ out)                // [8192][4096]
{
    __shared__ __align__(16) unsigned short As[2][256 * 64];
    __shared__ __align__(16) unsigned short Bs[2][256 * 64];

    const int bid = blockIdx.x;
    const int g   = bid & 7;          // group == XCD (round-robin dispatch)
    const int rem = bid >> 3;
    const int nt  = rem & 1;
    const int mt  = rem >> 1;         // 0..31

    const int tid  = threadIdx.x;
    const int lane = tid & 63;
    const int wid  = tid >> 6;        // 0..7
    const int wm   = wid >> 2;        // 0..1
    const int wn   = wid & 3;         // 0..3
    const int lr   = lane & 15;
    const int lg   = lane >> 4;

    fv4 acc[8][4];
#pragma unroll
    for (int i = 0; i < 8; ++i)
#pragma unroll
        for (int j = 0; j < 4; ++j)
            acc[i][j] = (fv4){0.f, 0.f, 0.f, 0.f};

    const float* xg = x + (size_t)(mt * 256) * 4096 + g * 512;
    const unsigned short* bg = bT + ((size_t)g * 512 + nt * 256) * 512;

    // ---- A staging: thread -> k-chunk ac (8 floats), rows ar0 + {0,64,128,192}
    const int ac  = tid & 7;
    const int ar0 = tid >> 3;                         // 0..63
    const float* aSrc   = xg + (size_t)ar0 * 4096 + ac * 8;
    const int    aSlotB = (ac ^ (ar0 & 7)) * 16;      // swizzled 16B slot (byte)

    // ---- B staging via global_load_lds (linear dest, pre-swizzled source)
    const unsigned short* bSrc =
        bg + (size_t)(wid * 32 + (lane >> 3)) * 512 + ((lane & 7) ^ ((lane >> 3) & 7)) * 8;

    // ---- fragment read bases (bytes); row&7 == lr&7 for both A and B
    const int aReadBase = (wm * 128 + lr) * 128;
    const int bReadBase = (wn * 64 + lr) * 128;
    const int ks0 = ((0 + lg) ^ (lr & 7)) * 16;       // kk=0 slot byte
    const int ks1 = ((4 + lg) ^ (lr & 7)) * 16;       // kk=1 slot byte

    float4 arg_[8];    // in-flight A tile: rr*2 + half
    sv8 af[4][2], bf[2][2];

#define ISSUE_A(kt)                                                         \
    do { _Pragma("unroll") for (int rr = 0; rr < 4; ++rr) {                 \
        const float* s_ = aSrc + (size_t)rr * 64 * 4096 + (kt) * 64;        \
        arg_[rr * 2 + 0] = *(const float4*)s_;                              \
        arg_[rr * 2 + 1] = *(const float4*)(s_ + 4);                        \
    } } while (0)

#define ISSUE_B(kt, bufw)                                                   \
    do { _Pragma("unroll") for (int p = 0; p < 4; ++p)                      \
        gl_lds16(bSrc + (size_t)p * 8 * 512 + (kt) * 64,                    \
                 (char*)&Bs[bufw][0] + (wid * 32 + p * 8) * 128);           \
    } while (0)

#define WRITE_A(bufw)                                                       \
    do { _Pragma("unroll") for (int rr = 0; rr < 4; ++rr) {                 \
        uint4 w_;                                                           \
        w_.x = pk2(arg_[rr * 2].x,     arg_[rr * 2].y);                     \
        w_.y = pk2(arg_[rr * 2].z,     arg_[rr * 2].w);                     \
        w_.z = pk2(arg_[rr * 2 + 1].x, arg_[rr * 2 + 1].y);                 \
        w_.w = pk2(arg_[rr * 2 + 1].z, arg_[rr * 2 + 1].w);                 \
        *(uint4*)((char*)&As[bufw][0] + (ar0 + rr * 64) * 128 + aSlotB) = w_; \
    } } while (0)

#define READ_A(mh)                                                          \
    do { _Pragma("unroll") for (int i = 0; i < 4; ++i) {                    \
        const char* p_ = (const char*)&As[buf][0] + aReadBase + ((mh) * 64 + i * 16) * 128; \
        af[i][0] = *(const sv8*)(p_ + ks0);                                 \
        af[i][1] = *(const sv8*)(p_ + ks1);                                 \
    } } while (0)

#define READ_B(nh)                                                          \
    do { _Pragma("unroll") for (int j = 0; j < 2; ++j) {                    \
        const char* p_ = (const char*)&Bs[buf][0] + bReadBase + ((nh) * 32 + j * 16) * 128; \
        bf[j][0] = *(const sv8*)(p_ + ks0);                                 \
        bf[j][1] = *(const sv8*)(p_ + ks1);                                 \
    } } while (0)

    // operand order (b, a): D row-index <- B (n), D col (lane&15) <- A (m),
    // so each lane holds 4 consecutive n values -> float4 epilogue stores.
#define MFMA_PH(mh, nh)                                                     \
    do { _Pragma("unroll") for (int i = 0; i < 4; ++i)                      \
         _Pragma("unroll") for (int j = 0; j < 2; ++j) {                    \
        acc[(mh) * 4 + i][(nh) * 2 + j] = __builtin_amdgcn_mfma_f32_16x16x32_bf16( \
            bf[j][0], af[i][0], acc[(mh) * 4 + i][(nh) * 2 + j], 0, 0, 0);  \
        acc[(mh) * 4 + i][(nh) * 2 + j] = __builtin_amdgcn_mfma_f32_16x16x32_bf16( \
            bf[j][1], af[i][1], acc[(mh) * 4 + i][(nh) * 2 + j], 0, 0, 0);  \
    } } while (0)

    // ---- prologue: tile 0 staged, tile 1 A-loads in flight ----
    ISSUE_A(0);          // 8 loads
    ISSUE_B(0, 0);       // 4 gl_lds
    WRITE_A(0);          // compiler waits the 8 A loads (vmcnt(4))
    ISSUE_A(1);          // 8 loads -> outstanding: 4 B + 8 A
    VM(8);               // B(0) landed
    LGKM0();             // our ds_writes done
    BAR();

    int buf = 0;
#pragma unroll 1
    for (int t = 0; t < 7; ++t) {
        const int nbuf = buf ^ 1;
        // P1 ------------------------------------------------------------
        READ_A(0); READ_B(0);
        BAR(); LGKM0();
        PRIO1(); MFMA_PH(0, 0); PRIO0();
        // P2 ------------------------------------------------------------
        ISSUE_B(t + 1, nbuf);          // outstanding: 8 A(t+1) + 4 B(t+1)
        READ_B(1);
        BAR(); LGKM0();
        PRIO1(); MFMA_PH(0, 1); PRIO0();
        // P3 ------------------------------------------------------------
        VM(4);                         // A(t+1) landed; B(t+1) still out
        WRITE_A(nbuf);
        READ_A(1); READ_B(0);
        BAR(); LGKM0();
        PRIO1(); MFMA_PH(1, 0); PRIO0();
        // P4 ------------------------------------------------------------
        ISSUE_A(t + 2 < 8 ? t + 2 : 7);  // outstanding: 4 B(t+1) + 8 A(t+2)
        READ_B(1);
        BAR(); LGKM0();
        PRIO1(); MFMA_PH(1, 1); PRIO0();
        VM(8);                         // B(t+1) landed; A(t+2) still out
        BAR();
        buf = nbuf;
    }

    // keep the final (unconsumed) prefetch loads live so vmcnt counts stay valid
    asm volatile("" :: "v"(arg_[0].x), "v"(arg_[1].x), "v"(arg_[2].x), "v"(arg_[3].x),
                       "v"(arg_[4].x), "v"(arg_[5].x), "v"(arg_[6].x), "v"(arg_[7].x));

    // ---- final tile (buf == 1), no staging ----
    READ_A(0); READ_B(0); LGKM0(); MFMA_PH(0, 0);
    READ_B(1);            LGKM0(); MFMA_PH(0, 1);
    READ_A(1); READ_B(0); LGKM0(); MFMA_PH(1, 0);
    READ_B(1);            LGKM0(); MFMA_PH(1, 1);

    // ---- epilogue: float4 stores (lane holds 4 consecutive n) ----
    float* og = out + (size_t)(mt * 256 + wm * 128) * 4096 + g * 512 + nt * 256 + wn * 64;
#pragma unroll
    for (int i = 0; i < 8; ++i)
#pragma unroll
        for (int j = 0; j < 4; ++j) {
            float4 v;
            v.x = acc[i][j][0]; v.y = acc[i][j][1];
            v.z = acc[i][j][2]; v.w = acc[i][j][3];
            *(float4*)(og + (size_t)(i * 16 + lr) * 4096 + j * 16 + lg * 4) = v;
        }

#undef ISSUE_A
#undef ISSUE_B
#undef WRITE_A
#undef READ_A
#undef READ_B
#undef MFMA_PH
}

// Safety net if ws is too small for the bf16 transposed blocks (4 MiB).
__global__ void bl_fallback(const float* __restrict__ x,
                            const float* __restrict__ blocks,
                            float* __restrict__ out) {
    const int o = blockIdx.x * 256 + threadIdx.x;
    const int col = o & 4095;
    const int row = o >> 12;
    const int g = col >> 9;
    const int n = col & 511;
    const float* xr = x + (size_t)row * 4096 + g * 512;
    const float* wp = blocks + (size_t)g * 512 * 512 + n;
    float s = 0.f;
    for (int m = 0; m < 512; ++m) s += xr[m] * wp[(size_t)m * 512];
    out[o] = s;
}

extern "C" void kernel_launch(void* const* d_in, const int* in_sizes, int n_in,
                              void* d_out, int out_size, void* d_ws, size_t ws_size,
                              hipStream_t stream) {
    const float* x      = (const float*)d_in[0];
    const float* blocks = (const float*)d_in[1];
    float* out          = (float*)d_out;

    const size_t need = (size_t)8 * 512 * 512 * sizeof(unsigned short); // 4 MiB
    if (ws_size >= need) {
        unsigned short* bT = (unsigned short*)d_ws;
        bl_transpose<<<dim3(8, 8, 8), 256, 0, stream>>>(blocks, bT);
        bl_gemm<<<512, 512, 0, stream>>>(x, bT, out);
    } else {
        bl_fallback<<<(8192 * 4096) / 256, 256, 0, stream>>>(x, blocks, out);
    }
}